// Round 19
// baseline (72.132 us; speedup 1.0000x reference)
//
#include <hip/hip_runtime.h>

#define S_LEN 8192
#define DIM   256
#define CHUNK 512
#define TB    64
#define NIT   8
#define NBLK  256

typedef __attribute__((ext_vector_type(8))) short          short8;
typedef __attribute__((ext_vector_type(4))) unsigned short u16x4;
typedef __attribute__((ext_vector_type(4))) unsigned int   u32x4;
typedef __attribute__((ext_vector_type(4))) float          f32x4;
typedef __attribute__((ext_vector_type(8))) __bf16         bf16x8;

// native cast -> v_cvt RNE
static __device__ __forceinline__ unsigned short f2bf(float f){
  return __builtin_bit_cast(unsigned short, (__bf16)f);
}
static __device__ __forceinline__ unsigned pk2bf(float lo, float hi){
  return (unsigned)f2bf(lo) | ((unsigned)f2bf(hi) << 16);
}
static __device__ __forceinline__ float bf2f(unsigned short h){
  unsigned int u = ((unsigned int)h) << 16;
  return __builtin_bit_cast(float, u);
}
static __device__ __forceinline__ float fast_tanh(float x){
  float e = __expf(2.0f * x);
  return 1.0f - 2.0f / (e + 1.0f);
}
static __device__ __forceinline__ f32x4 mfma_bf16(short8 a, short8 b, f32x4 c){
  return __builtin_amdgcn_mfma_f32_16x16x32_bf16(
      __builtin_bit_cast(bf16x8, a), __builtin_bit_cast(bf16x8, b), c, 0, 0, 0);
}
// barrier draining LDS ops only (no vmcnt drain)
static __device__ __forceinline__ void softbar(){
  asm volatile("s_waitcnt lgkmcnt(0)\n\ts_barrier" ::: "memory");
}

// sXB : (r,d) at dblk*2048 + srow*32 + off; dblk=d>>4, srow=r^(dblk&3),
//       off=((d&15)*2)^(((srow>>2)&1)<<4)        (d-contig, GEMM1-B)  [R5-verified]
// sXT2: (r,d) at buf*32768 + d*128 + ((r*2)^(key(d)<<4)), key=((d&3)<<1)^((d>>2)&7)
//       (r-contig, GEMM3-B)  [R5-verified, double-buffered]
// Schedule [R13-verified]: 2 barriers/iter
//   A(t): GEMM3(t-1) || GEMM1(t) -> sT2
//   B(t): GEMM2(t)+exp -> sPT[t&1] (waves 0-3) || stage t+1 || prefetch t+2
// Epilogue: decoupled last-block-done merge (release wbl2 / device atomic / acquire inv)

__global__ __launch_bounds__(512, 2) void k_main(
    const float* __restrict__ x, const int* __restrict__ mask,
    const float* __restrict__ ok, const float* __restrict__ kk,
    float* __restrict__ ACC, float* __restrict__ ML,
    int* __restrict__ CNT, float* __restrict__ out)
{
  __shared__ __align__(16) unsigned char sXB [32768];
  __shared__ __align__(16) unsigned char sXT2[65536];   // 2 buffers
  __shared__ __align__(16) unsigned char sT2 [32768];   // tanh(h) [64][256] bf16, swz ((row&7)<<4)
  __shared__ __align__(16) unsigned char sOT [8*528];   // O^T [8 head][256] bf16 (+pad)
  __shared__ __align__(16) unsigned char sPT [2*2304];  // P^T [16][64] bf16 (+pad), 2 buffers
  __shared__ float sWSum[4][16];
  __shared__ float sMaskB[CHUNK];
  __shared__ int   sIsLast;
  __shared__ float sLh[8];

  const int tid = threadIdx.x;
  const int w   = tid >> 6;      // wave 0..7
  const int l   = tid & 63;
  const int l15 = l & 15;
  const int lhi = l >> 4;        // 0..3
  const int bid = blockIdx.x;
  const int b   = bid >> 4;
  const int chunk0 = (bid & 15) * CHUNK;

  // O^T init (8 real heads only; GEMM2 zero-fills lanes l15>=8)
  for (int idx = tid; idx < 8 * 256; idx += 512){
    int h = idx >> 8, k = idx & 255;
    *(unsigned short*)(sOT + h * 528 + k * 2) = f2bf(ok[k * 8 + h]);
  }
  sMaskB[tid] = mask[(size_t)b * S_LEN + chunk0 + tid] ? 0.0f : 1e12f;

  // persistent K^T fragments built directly from kk (fp32, transposed reads) [R18]
  short8 aF[2][8];
  #pragma unroll
  for (int mi = 0; mi < 2; ++mi){
    int hidA = l15 + ((2*w + mi) << 4);
    #pragma unroll
    for (int k8 = 0; k8 < 8; ++k8){
      int col = (k8 << 5) + (lhi << 3);
      short8 v;
      #pragma unroll
      for (int e = 0; e < 8; ++e)
        v[e] = (short)f2bf(kk[(size_t)(col + e) * 256 + hidA]);
      aF[mi][k8] = v;
    }
  }

  const unsigned char* xb = (const unsigned char*)(x + ((size_t)b * S_LEN + chunk0) * DIM);
  const int dblk = l >> 2;

  // ---- prologue: tile 0 -> regs -> stage sXB + sXT2[0]; then load xr <- tile 1
  f32x4 xr[8];
  #pragma unroll
  for (int q = 0; q < 8; ++q)
    xr[q] = *(const f32x4*)(xb + (((size_t)(8*w + q)) * DIM + 4*l) * 4);

  {
    unsigned vd[8][2];
    #pragma unroll
    for (int q = 0; q < 8; ++q){
      vd[q][0] = pk2bf(xr[q][0], xr[q][1]);
      vd[q][1] = pk2bf(xr[q][2], xr[q][3]);
    }
    #pragma unroll
    for (int q = 0; q < 8; ++q){
      int r = 8*w + q;
      int srow = r ^ (dblk & 3);
      int off = ((l & 3) * 8) ^ (((srow >> 2) & 1) << 4);
      *(uint2*)(sXB + dblk * 2048 + srow * 32 + off) = make_uint2(vd[q][0], vd[q][1]);
    }
    #pragma unroll
    for (int i = 0; i < 4; ++i){
      int hh = i >> 1;
      unsigned dwv[4];
      #pragma unroll
      for (int j = 0; j < 4; ++j){
        unsigned a = vd[2*j][hh], c = vd[2*j+1][hh];
        dwv[j] = (i & 1) ? ((a >> 16) | (c & 0xFFFF0000u)) : ((a & 0xFFFFu) | (c << 16));
      }
      int d = 4*l + i;
      int key = ((d & 3) << 1) ^ ((d >> 2) & 7);
      *(u32x4*)(sXT2 + d * 128 + ((16*w) ^ (key << 4))) = (u32x4){dwv[0],dwv[1],dwv[2],dwv[3]};
    }
  }
  #pragma unroll
  for (int q = 0; q < 8; ++q)
    xr[q] = *(const f32x4*)(xb + (((size_t)(TB + 8*w + q)) * DIM + 4*l) * 4);

  f32x4 acc3[2];
  acc3[0] = (f32x4){0.f,0.f,0.f,0.f};
  acc3[1] = acc3[0];
  float Lrun = 0.0f;    // per-lane partial; shuffle-reduced once in epilogue

  __syncthreads();

  for (int it = 0; it < NIT; ++it){
    // ======== Phase A: GEMM3(it-1) || GEMM1(it) + tanh -> sT2 ========
    if (it > 0){
      const int pb = (it - 1) & 1;
      short8 aP0 = *(const short8*)(sPT + pb * 2304 + l15 * 144 + lhi * 16);       // r 0..31
      short8 aP1 = *(const short8*)(sPT + pb * 2304 + l15 * 144 + 64 + lhi * 16);  // r 32..63
      const unsigned char* srcX = sXT2 + pb * 32768;
      #pragma unroll
      for (int mi = 0; mi < 2; ++mi){
        int d = (2*w + mi) * 16 + l15;
        int key = ((d & 3) << 1) ^ ((d >> 2) & 7);
        const unsigned char* pd = srcX + d * 128;
        short8 b0 = *(const short8*)(pd + (((     lhi * 16)) ^ (key << 4)));
        short8 b1 = *(const short8*)(pd + (((64 + lhi * 16)) ^ (key << 4)));
        acc3[mi] = mfma_bf16(aP0, b0, acc3[mi]);
        acc3[mi] = mfma_bf16(aP1, b1, acc3[mi]);
      }
    }
    #pragma unroll
    for (int nt = 0; nt < 4; ++nt){
      int row = l15 + (nt << 4);
      f32x4 a0 = (f32x4){0.f,0.f,0.f,0.f};
      f32x4 a1 = a0;
      __builtin_amdgcn_s_setprio(1);
      #pragma unroll
      for (int k8 = 0; k8 < 8; ++k8){
        int dblkR = k8 * 2 + (lhi >> 1);
        int srowB = row ^ (dblkR & 3);
        int off = ((lhi & 1) * 16) ^ (((srowB >> 2) & 1) << 4);
        short8 bF = *(const short8*)(sXB + dblkR * 2048 + srowB * 32 + off);
        a0 = mfma_bf16(aF[0][k8], bF, a0);
        a1 = mfma_bf16(aF[1][k8], bF, a1);
      }
      __builtin_amdgcn_s_setprio(0);
      #pragma unroll
      for (int mi = 0; mi < 2; ++mi){
        f32x4 av = mi ? a1 : a0;
        u16x4 tv;
        #pragma unroll
        for (int r = 0; r < 4; ++r) tv[r] = f2bf(fast_tanh(av[r]));
        int hidb2 = ((((2*w + mi) << 4) + (lhi << 2))) * 2;
        *(u16x4*)(sT2 + row * 512 + (hidb2 ^ ((row & 7) << 4))) = tv;
      }
    }
    softbar();

    // ======== Phase B: GEMM2(it)+exp (waves 0-3) || stage tile it+1 || prefetch it+2 ========
    if (it + 1 < NIT){
      unsigned vd[8][2];
      #pragma unroll
      for (int q = 0; q < 8; ++q){
        vd[q][0] = pk2bf(xr[q][0], xr[q][1]);
        vd[q][1] = pk2bf(xr[q][2], xr[q][3]);
      }
      #pragma unroll
      for (int q = 0; q < 8; ++q){
        int r = 8*w + q;
        int srow = r ^ (dblk & 3);
        int off = ((l & 3) * 8) ^ (((srow >> 2) & 1) << 4);
        *(uint2*)(sXB + dblk * 2048 + srow * 32 + off) = make_uint2(vd[q][0], vd[q][1]);
      }
      unsigned char* dst = sXT2 + ((it + 1) & 1) * 32768;
      #pragma unroll
      for (int i = 0; i < 4; ++i){
        int hh = i >> 1;
        unsigned dwv[4];
        #pragma unroll
        for (int j = 0; j < 4; ++j){
          unsigned a = vd[2*j][hh], c = vd[2*j+1][hh];
          dwv[j] = (i & 1) ? ((a >> 16) | (c & 0xFFFF0000u)) : ((a & 0xFFFFu) | (c << 16));
        }
        int d = 4*l + i;
        int key = ((d & 3) << 1) ^ ((d >> 2) & 7);
        *(u32x4*)(dst + d * 128 + ((16*w) ^ (key << 4))) = (u32x4){dwv[0],dwv[1],dwv[2],dwv[3]};
      }
    }
    if (w < 4){
      int row = l15 + (w << 4);
      // dual accumulator: halves the serial MFMA chain (k 0-3 || k 4-7)
      f32x4 a2a = (f32x4){0.f,0.f,0.f,0.f};
      f32x4 a2b = a2a;
      __builtin_amdgcn_s_setprio(1);
      #pragma unroll
      for (int k = 0; k < 4; ++k){
        int col2a = (k << 6) + (lhi << 4);
        int col2b = ((k + 4) << 6) + (lhi << 4);
        short8 aTa = *(const short8*)(sT2 + row * 512 + (col2a ^ ((row & 7) << 4)));
        short8 aTb = *(const short8*)(sT2 + row * 512 + (col2b ^ ((row & 7) << 4)));
        short8 bOa = (l15 < 8) ? *(const short8*)(sOT + l15 * 528 + col2a)
                               : (short8){0,0,0,0,0,0,0,0};
        short8 bOb = (l15 < 8) ? *(const short8*)(sOT + l15 * 528 + col2b)
                               : (short8){0,0,0,0,0,0,0,0};
        a2a = mfma_bf16(aTa, bOa, a2a);
        a2b = mfma_bf16(aTb, bOb, a2b);
      }
      __builtin_amdgcn_s_setprio(0);
      f32x4 a2 = a2a + a2b;
      int rbase = (w << 4) + (lhi << 2);
      #pragma unroll
      for (int r = 0; r < 4; ++r){
        // no-max softmax [R11-verified]: |sc| small; masked rows exp(-1e12)=0
        float p = __expf(a2[r] - sMaskB[it * TB + rbase + r]);
        unsigned short pb2 = f2bf(p);
        Lrun += bf2f(pb2);          // per-lane partial; reduced in epilogue
        *(unsigned short*)(sPT + (it & 1) * 2304 + l15 * 144 + (rbase + r) * 2) = pb2;
      }
    }
    if (it + 2 < NIT){
      #pragma unroll
      for (int q = 0; q < 8; ++q)
        xr[q] = *(const f32x4*)(xb + (((size_t)((it+2)*TB + 8*w + q)) * DIM + 4*l) * 4);
    }
    softbar();
  }

  // ---- epilogue GEMM3 for the last tile ----
  {
    const int pb = (NIT - 1) & 1;
    short8 aP0 = *(const short8*)(sPT + pb * 2304 + l15 * 144 + lhi * 16);
    short8 aP1 = *(const short8*)(sPT + pb * 2304 + l15 * 144 + 64 + lhi * 16);
    const unsigned char* srcX = sXT2 + pb * 32768;
    #pragma unroll
    for (int mi = 0; mi < 2; ++mi){
      int d = (2*w + mi) * 16 + l15;
      int key = ((d & 3) << 1) ^ ((d >> 2) & 7);
      const unsigned char* pd = srcX + d * 128;
      short8 b0 = *(const short8*)(pd + (((     lhi * 16)) ^ (key << 4)));
      short8 b1 = *(const short8*)(pd + (((64 + lhi * 16)) ^ (key << 4)));
      acc3[mi] = mfma_bf16(aP0, b0, acc3[mi]);
      acc3[mi] = mfma_bf16(aP1, b1, acc3[mi]);
    }
  }

  // ---- epilogue: per-chunk partials -> global ----
  if (lhi < 2){      // only heads 0..7 are real
    #pragma unroll
    for (int mi = 0; mi < 2; ++mi){
      int d = ((2*w + mi) << 4) + l15;
      #pragma unroll
      for (int r = 0; r < 4; ++r){
        int h = (lhi << 2) + r;
        ACC[((size_t)bid * 8 + h) * 256 + d] = acc3[mi][r];
      }
    }
  }
  if (w < 4){
    Lrun += __shfl_xor(Lrun, 16);
    Lrun += __shfl_xor(Lrun, 32);
    if (l < 16) sWSum[w][l] = Lrun;
  }
  __syncthreads();
  if (tid < 8)
    ML[bid * 8 + tid] = sWSum[0][tid] + sWSum[1][tid] + sWSum[2][tid] + sWSum[3][tid];

  // ---- decoupled last-block-done merge ----
  __syncthreads();                 // drains every wave's stores (vmcnt0 per wave)
  if (tid == 0){
    __threadfence();               // release: write back L2 to coherence point
    int old = atomicAdd(&CNT[b], 1);
    sIsLast = (old == 15);
    __threadfence();               // acquire: invalidate L1/L2 before merge reads
  }
  __syncthreads();
  if (sIsLast){
    if (tid < 8){
      float L = 0.0f;
      #pragma unroll
      for (int c = 0; c < 16; ++c) L += ML[(b * 16 + c) * 8 + tid];
      sLh[tid] = L;
    }
    __syncthreads();
    for (int j = tid; j < 2048; j += 512){
      int h = j >> 8, d = j & 255;
      float V = 0.0f;
      #pragma unroll 4
      for (int c = 0; c < 16; ++c)
        V += ACC[((size_t)((b * 16 + c) * 8 + h)) * 256 + d];
      out[(size_t)b * 2048 + j] = V / sLh[h];
    }
  }
}

extern "C" void kernel_launch(void* const* d_in, const int* in_sizes, int n_in,
                              void* d_out, int out_size, void* d_ws, size_t ws_size,
                              hipStream_t stream){
  const float* x   = (const float*)d_in[0];
  const int*  mask = (const int*) d_in[1];
  const float* kk  = (const float*)d_in[2];
  const float* ok  = (const float*)d_in[3];
  float* out = (float*)d_out;

  // ws layout: ACC f32 256*8*256 (2 MiB) | ML f32 256*8 (8 KiB) | CNT int[16]
  float* ACC = (float*)d_ws;
  float* ML  = (float*)((char*)d_ws + 2097152);
  int*   CNT = (int*)  ((char*)d_ws + 2097152 + 8192);

  hipMemsetAsync(CNT, 0, 16 * sizeof(int), stream);
  k_main<<<NBLK, 512, 0, stream>>>(x, mask, ok, kk, ACC, ML, CNT, out);
}

// Round 20
// 53.036 us; speedup vs baseline: 1.3601x; 1.3601x over previous
//
#include <hip/hip_runtime.h>

#define S_LEN 8192
#define DIM   256
#define CHUNK 512
#define TB    64
#define NIT   8
#define NBLK  256

typedef __attribute__((ext_vector_type(8))) short          short8;
typedef __attribute__((ext_vector_type(4))) unsigned short u16x4;
typedef __attribute__((ext_vector_type(4))) unsigned int   u32x4;
typedef __attribute__((ext_vector_type(4))) float          f32x4;
typedef __attribute__((ext_vector_type(8))) __bf16         bf16x8;

// native cast -> v_cvt RNE
static __device__ __forceinline__ unsigned short f2bf(float f){
  return __builtin_bit_cast(unsigned short, (__bf16)f);
}
static __device__ __forceinline__ unsigned pk2bf(float lo, float hi){
  return (unsigned)f2bf(lo) | ((unsigned)f2bf(hi) << 16);
}
static __device__ __forceinline__ float bf2f(unsigned short h){
  unsigned int u = ((unsigned int)h) << 16;
  return __builtin_bit_cast(float, u);
}
static __device__ __forceinline__ float fast_tanh(float x){
  float e = __expf(2.0f * x);
  return 1.0f - 2.0f / (e + 1.0f);
}
static __device__ __forceinline__ f32x4 mfma_bf16(short8 a, short8 b, f32x4 c){
  return __builtin_amdgcn_mfma_f32_16x16x32_bf16(
      __builtin_bit_cast(bf16x8, a), __builtin_bit_cast(bf16x8, b), c, 0, 0, 0);
}
// barrier draining LDS ops only (no vmcnt drain)
static __device__ __forceinline__ void softbar(){
  asm volatile("s_waitcnt lgkmcnt(0)\n\ts_barrier" ::: "memory");
}

// sXB : (r,d) at dblk*2048 + srow*32 + off; dblk=d>>4, srow=r^(dblk&3),
//       off=((d&15)*2)^(((srow>>2)&1)<<4)        (d-contig, GEMM1-B)  [R5-verified]
// sXT2: (r,d) at buf*32768 + d*128 + ((r*2)^(key(d)<<4)), key=((d&3)<<1)^((d>>2)&7)
//       (r-contig, GEMM3-B)  [R5-verified, double-buffered]
// Schedule [R13-verified]: 2 barriers/iter
//   A(t): GEMM3(t-1) [sXT2[(t-1)&1], sPT[(t-1)&1]]  ||  GEMM1(t) [sXB] -> sT2
//   B(t): GEMM2(t)+exp -> sPT[t&1] (waves 0-3)  ||  stage t+1 -> sXB+sXT2[(t+1)&1]
//         || prefetch xr <- t+2

__global__ __launch_bounds__(512, 2) void k_main(
    const float* __restrict__ x, const int* __restrict__ mask,
    const float* __restrict__ ok, const float* __restrict__ kk,
    float* __restrict__ ACC, float* __restrict__ ML)
{
  __shared__ __align__(16) unsigned char sXB [32768];
  __shared__ __align__(16) unsigned char sXT2[65536];   // 2 buffers
  __shared__ __align__(16) unsigned char sT2 [32768];   // tanh(h) [64][256] bf16, swz ((row&7)<<4)
  __shared__ __align__(16) unsigned char sOT [8*528];   // O^T [8 head][256] bf16 (+pad)
  __shared__ __align__(16) unsigned char sPT [2*2304];  // P^T [16][64] bf16 (+pad), 2 buffers
  __shared__ float sWSum[4][16];
  __shared__ float sMaskB[CHUNK];

  const int tid = threadIdx.x;
  const int w   = tid >> 6;      // wave 0..7
  const int l   = tid & 63;
  const int l15 = l & 15;
  const int lhi = l >> 4;        // 0..3
  const int bid = blockIdx.x;
  const int b   = bid >> 4;
  const int chunk0 = (bid & 15) * CHUNK;

  // O^T init (8 real heads only; GEMM2 zero-fills lanes l15>=8)
  for (int idx = tid; idx < 8 * 256; idx += 512){
    int h = idx >> 8, k = idx & 255;
    *(unsigned short*)(sOT + h * 528 + k * 2) = f2bf(ok[k * 8 + h]);
  }
  sMaskB[tid] = mask[(size_t)b * S_LEN + chunk0 + tid] ? 0.0f : 1e12f;

  // persistent K^T fragments built directly from kk (fp32, transposed reads) [R18]
  short8 aF[2][8];
  #pragma unroll
  for (int mi = 0; mi < 2; ++mi){
    int hidA = l15 + ((2*w + mi) << 4);
    #pragma unroll
    for (int k8 = 0; k8 < 8; ++k8){
      int col = (k8 << 5) + (lhi << 3);
      short8 v;
      #pragma unroll
      for (int e = 0; e < 8; ++e)
        v[e] = (short)f2bf(kk[(size_t)(col + e) * 256 + hidA]);
      aF[mi][k8] = v;
    }
  }

  const unsigned char* xb = (const unsigned char*)(x + ((size_t)b * S_LEN + chunk0) * DIM);
  const int dblk = l >> 2;

  // ---- prologue: tile 0 -> regs -> stage sXB + sXT2[0]; then load xr <- tile 1
  f32x4 xr[8];
  #pragma unroll
  for (int q = 0; q < 8; ++q)
    xr[q] = *(const f32x4*)(xb + (((size_t)(8*w + q)) * DIM + 4*l) * 4);

  {
    unsigned vd[8][2];
    #pragma unroll
    for (int q = 0; q < 8; ++q){
      vd[q][0] = pk2bf(xr[q][0], xr[q][1]);
      vd[q][1] = pk2bf(xr[q][2], xr[q][3]);
    }
    #pragma unroll
    for (int q = 0; q < 8; ++q){
      int r = 8*w + q;
      int srow = r ^ (dblk & 3);
      int off = ((l & 3) * 8) ^ (((srow >> 2) & 1) << 4);
      *(uint2*)(sXB + dblk * 2048 + srow * 32 + off) = make_uint2(vd[q][0], vd[q][1]);
    }
    #pragma unroll
    for (int i = 0; i < 4; ++i){
      int hh = i >> 1;
      unsigned dwv[4];
      #pragma unroll
      for (int j = 0; j < 4; ++j){
        unsigned a = vd[2*j][hh], c = vd[2*j+1][hh];
        dwv[j] = (i & 1) ? ((a >> 16) | (c & 0xFFFF0000u)) : ((a & 0xFFFFu) | (c << 16));
      }
      int d = 4*l + i;
      int key = ((d & 3) << 1) ^ ((d >> 2) & 7);
      *(u32x4*)(sXT2 + d * 128 + ((16*w) ^ (key << 4))) = (u32x4){dwv[0],dwv[1],dwv[2],dwv[3]};
    }
  }
  #pragma unroll
  for (int q = 0; q < 8; ++q)
    xr[q] = *(const f32x4*)(xb + (((size_t)(TB + 8*w + q)) * DIM + 4*l) * 4);

  f32x4 acc3[2];
  acc3[0] = (f32x4){0.f,0.f,0.f,0.f};
  acc3[1] = acc3[0];
  float Lrun = 0.0f;    // per-lane partial; shuffle-reduced once in epilogue

  __syncthreads();

  for (int it = 0; it < NIT; ++it){
    // ======== Phase A: GEMM3(it-1) || GEMM1(it) + tanh -> sT2 ========
    if (it > 0){
      const int pb = (it - 1) & 1;
      short8 aP0 = *(const short8*)(sPT + pb * 2304 + l15 * 144 + lhi * 16);       // r 0..31
      short8 aP1 = *(const short8*)(sPT + pb * 2304 + l15 * 144 + 64 + lhi * 16);  // r 32..63
      const unsigned char* srcX = sXT2 + pb * 32768;
      #pragma unroll
      for (int mi = 0; mi < 2; ++mi){
        int d = (2*w + mi) * 16 + l15;
        int key = ((d & 3) << 1) ^ ((d >> 2) & 7);
        const unsigned char* pd = srcX + d * 128;
        short8 b0 = *(const short8*)(pd + (((     lhi * 16)) ^ (key << 4)));
        short8 b1 = *(const short8*)(pd + (((64 + lhi * 16)) ^ (key << 4)));
        acc3[mi] = mfma_bf16(aP0, b0, acc3[mi]);
        acc3[mi] = mfma_bf16(aP1, b1, acc3[mi]);
      }
    }
    #pragma unroll
    for (int nt = 0; nt < 4; ++nt){
      int row = l15 + (nt << 4);
      f32x4 a0 = (f32x4){0.f,0.f,0.f,0.f};
      f32x4 a1 = a0;
      __builtin_amdgcn_s_setprio(1);
      #pragma unroll
      for (int k8 = 0; k8 < 8; ++k8){
        int dblkR = k8 * 2 + (lhi >> 1);
        int srowB = row ^ (dblkR & 3);
        int off = ((lhi & 1) * 16) ^ (((srowB >> 2) & 1) << 4);
        short8 bF = *(const short8*)(sXB + dblkR * 2048 + srowB * 32 + off);
        a0 = mfma_bf16(aF[0][k8], bF, a0);
        a1 = mfma_bf16(aF[1][k8], bF, a1);
      }
      __builtin_amdgcn_s_setprio(0);
      #pragma unroll
      for (int mi = 0; mi < 2; ++mi){
        f32x4 av = mi ? a1 : a0;
        u16x4 tv;
        #pragma unroll
        for (int r = 0; r < 4; ++r) tv[r] = f2bf(fast_tanh(av[r]));
        int hidb2 = ((((2*w + mi) << 4) + (lhi << 2))) * 2;
        *(u16x4*)(sT2 + row * 512 + (hidb2 ^ ((row & 7) << 4))) = tv;
      }
    }
    softbar();

    // ======== Phase B: GEMM2(it)+exp (waves 0-3) || stage tile it+1 || prefetch it+2 ========
    if (it + 1 < NIT){
      unsigned vd[8][2];
      #pragma unroll
      for (int q = 0; q < 8; ++q){
        vd[q][0] = pk2bf(xr[q][0], xr[q][1]);
        vd[q][1] = pk2bf(xr[q][2], xr[q][3]);
      }
      #pragma unroll
      for (int q = 0; q < 8; ++q){
        int r = 8*w + q;
        int srow = r ^ (dblk & 3);
        int off = ((l & 3) * 8) ^ (((srow >> 2) & 1) << 4);
        *(uint2*)(sXB + dblk * 2048 + srow * 32 + off) = make_uint2(vd[q][0], vd[q][1]);
      }
      unsigned char* dst = sXT2 + ((it + 1) & 1) * 32768;
      #pragma unroll
      for (int i = 0; i < 4; ++i){
        int hh = i >> 1;
        unsigned dwv[4];
        #pragma unroll
        for (int j = 0; j < 4; ++j){
          unsigned a = vd[2*j][hh], c = vd[2*j+1][hh];
          dwv[j] = (i & 1) ? ((a >> 16) | (c & 0xFFFF0000u)) : ((a & 0xFFFFu) | (c << 16));
        }
        int d = 4*l + i;
        int key = ((d & 3) << 1) ^ ((d >> 2) & 7);
        *(u32x4*)(dst + d * 128 + ((16*w) ^ (key << 4))) = (u32x4){dwv[0],dwv[1],dwv[2],dwv[3]};
      }
    }
    if (w < 4){
      int row = l15 + (w << 4);
      // dual accumulator: halves the serial MFMA chain (k 0-3 || k 4-7)
      f32x4 a2a = (f32x4){0.f,0.f,0.f,0.f};
      f32x4 a2b = a2a;
      __builtin_amdgcn_s_setprio(1);
      #pragma unroll
      for (int k = 0; k < 4; ++k){
        int col2a = (k << 6) + (lhi << 4);
        int col2b = ((k + 4) << 6) + (lhi << 4);
        short8 aTa = *(const short8*)(sT2 + row * 512 + (col2a ^ ((row & 7) << 4)));
        short8 aTb = *(const short8*)(sT2 + row * 512 + (col2b ^ ((row & 7) << 4)));
        short8 bOa = (l15 < 8) ? *(const short8*)(sOT + l15 * 528 + col2a)
                               : (short8){0,0,0,0,0,0,0,0};
        short8 bOb = (l15 < 8) ? *(const short8*)(sOT + l15 * 528 + col2b)
                               : (short8){0,0,0,0,0,0,0,0};
        a2a = mfma_bf16(aTa, bOa, a2a);
        a2b = mfma_bf16(aTb, bOb, a2b);
      }
      __builtin_amdgcn_s_setprio(0);
      f32x4 a2 = a2a + a2b;
      int rbase = (w << 4) + (lhi << 2);
      #pragma unroll
      for (int r = 0; r < 4; ++r){
        // no-max softmax [R11-verified]: |sc| small; masked rows exp(-1e12)=0
        float p = __expf(a2[r] - sMaskB[it * TB + rbase + r]);
        unsigned short pb2 = f2bf(p);
        Lrun += bf2f(pb2);          // per-lane partial; reduced in epilogue
        *(unsigned short*)(sPT + (it & 1) * 2304 + l15 * 144 + (rbase + r) * 2) = pb2;
      }
    }
    if (it + 2 < NIT){
      #pragma unroll
      for (int q = 0; q < 8; ++q)
        xr[q] = *(const f32x4*)(xb + (((size_t)((it+2)*TB + 8*w + q)) * DIM + 4*l) * 4);
    }
    softbar();
  }

  // ---- epilogue GEMM3 for the last tile ----
  {
    const int pb = (NIT - 1) & 1;
    short8 aP0 = *(const short8*)(sPT + pb * 2304 + l15 * 144 + lhi * 16);
    short8 aP1 = *(const short8*)(sPT + pb * 2304 + l15 * 144 + 64 + lhi * 16);
    const unsigned char* srcX = sXT2 + pb * 32768;
    #pragma unroll
    for (int mi = 0; mi < 2; ++mi){
      int d = (2*w + mi) * 16 + l15;
      int key = ((d & 3) << 1) ^ ((d >> 2) & 7);
      const unsigned char* pd = srcX + d * 128;
      short8 b0 = *(const short8*)(pd + (((     lhi * 16)) ^ (key << 4)));
      short8 b1 = *(const short8*)(pd + (((64 + lhi * 16)) ^ (key << 4)));
      acc3[mi] = mfma_bf16(aP0, b0, acc3[mi]);
      acc3[mi] = mfma_bf16(aP1, b1, acc3[mi]);
    }
  }

  // epilogue: per-chunk partials.  acc3[mi]: head = lhi*4+reg, d = (2w+mi)*16 + l15
  if (lhi < 2){      // only heads 0..7 are real
    #pragma unroll
    for (int mi = 0; mi < 2; ++mi){
      int d = ((2*w + mi) << 4) + l15;
      #pragma unroll
      for (int r = 0; r < 4; ++r){
        int h = (lhi << 2) + r;
        ACC[((size_t)bid * 8 + h) * 256 + d] = acc3[mi][r];
      }
    }
  }
  if (w < 4){
    Lrun += __shfl_xor(Lrun, 16);
    Lrun += __shfl_xor(Lrun, 32);
    if (l < 16) sWSum[w][l] = Lrun;
  }
  __syncthreads();
  if (tid < 8)
    ML[bid * 8 + tid] = sWSum[0][tid] + sWSum[1][tid] + sWSum[2][tid] + sWSum[3][tid];
}

// ---- merge 16 chunk-partials per (batch, head): no max needed (fixed shift = 0)
__global__ void k_merge(const float* __restrict__ ACC, const float* __restrict__ ML,
                        float* __restrict__ out){
  int b = blockIdx.x >> 3;
  int h = blockIdx.x & 7;
  int d = threadIdx.x;                      // 256
  float L = 0.0f, V = 0.0f;
  #pragma unroll 4
  for (int c = 0; c < 16; ++c){
    int blk = b * 16 + c;
    L += ML[blk * 8 + h];
    V += ACC[((size_t)blk * 8 + h) * 256 + d];
  }
  out[(size_t)b * 2048 + h * 256 + d] = V / L;
}

extern "C" void kernel_launch(void* const* d_in, const int* in_sizes, int n_in,
                              void* d_out, int out_size, void* d_ws, size_t ws_size,
                              hipStream_t stream){
  const float* x   = (const float*)d_in[0];
  const int*  mask = (const int*) d_in[1];
  const float* kk  = (const float*)d_in[2];
  const float* ok  = (const float*)d_in[3];
  float* out = (float*)d_out;

  // ws layout: ACC f32 256*8*256 (2 MiB) | ML f32 256*8 (8 KiB)
  float* ACC = (float*)d_ws;
  float* ML  = (float*)((char*)d_ws + 2097152);

  k_main <<<NBLK, 512, 0, stream>>>(x, mask, ok, kk, ACC, ML);
  k_merge<<<128, 256, 0, stream>>>(ACC, ML, out);
}

// Round 22
// 52.938 us; speedup vs baseline: 1.3626x; 1.0018x over previous
//
#include <hip/hip_runtime.h>

#define S_LEN 8192
#define DIM   256
#define CHUNK 512
#define TB    64
#define NIT   8
#define NBLK  256

typedef __attribute__((ext_vector_type(8))) short          short8;
typedef __attribute__((ext_vector_type(4))) unsigned short u16x4;
typedef __attribute__((ext_vector_type(4))) unsigned int   u32x4;
typedef __attribute__((ext_vector_type(4))) float          f32x4;
typedef __attribute__((ext_vector_type(8))) __bf16         bf16x8;

// native cast -> v_cvt RNE
static __device__ __forceinline__ unsigned short f2bf(float f){
  return __builtin_bit_cast(unsigned short, (__bf16)f);
}
static __device__ __forceinline__ unsigned pk2bf(float lo, float hi){
  return (unsigned)f2bf(lo) | ((unsigned)f2bf(hi) << 16);
}
static __device__ __forceinline__ float bf2f(unsigned short h){
  unsigned int u = ((unsigned int)h) << 16;
  return __builtin_bit_cast(float, u);
}
static __device__ __forceinline__ float fast_tanh(float x){
  float e = __expf(2.0f * x);
  return 1.0f - 2.0f / (e + 1.0f);
}
static __device__ __forceinline__ f32x4 mfma_bf16(short8 a, short8 b, f32x4 c){
  return __builtin_amdgcn_mfma_f32_16x16x32_bf16(
      __builtin_bit_cast(bf16x8, a), __builtin_bit_cast(bf16x8, b), c, 0, 0, 0);
}
// barrier draining LDS ops only (no vmcnt drain)
static __device__ __forceinline__ void softbar(){
  asm volatile("s_waitcnt lgkmcnt(0)\n\ts_barrier" ::: "memory");
}

// sXB : (r,d) at dblk*2048 + srow*32 + off; dblk=d>>4, srow=r^(dblk&3),
//       off=((d&15)*2)^(((srow>>2)&1)<<4)        (d-contig, GEMM1-B)  [R5-verified]
// sXT2: (r,d) at buf*32768 + d*128 + ((r*2)^(key(d)<<4)), key=((d&3)<<1)^((d>>2)&7)
//       (r-contig, GEMM3-B)  [R5-verified, double-buffered]
// Schedule [R13-verified]: 2 barriers/iter
//   A(t): GEMM3(t-1) [sXT2[(t-1)&1], sPT[(t-1)&1]]  ||  GEMM1(t) [sXB] -> sT2
//   B(t): GEMM2(t)+exp -> sPT[t&1] (waves 0-3)  ||  stage t+1 -> sXB+sXT2[(t+1)&1]
//         || prefetch xr <- t+2

__global__ __launch_bounds__(512, 2) void k_main(
    const float* __restrict__ x, const int* __restrict__ mask,
    const float* __restrict__ ok, const float* __restrict__ kk,
    float* __restrict__ ACC, float* __restrict__ ML)
{
  __shared__ __align__(16) unsigned char sXB [32768];
  __shared__ __align__(16) unsigned char sXT2[65536];   // 2 buffers
  __shared__ __align__(16) unsigned char sT2 [32768];   // tanh(h) [64][256] bf16, swz ((row&7)<<4)
  __shared__ __align__(16) unsigned char sOT [8*528];   // O^T [8 head][256] bf16 (+pad)
  __shared__ __align__(16) unsigned char sPT [2*2304];  // P^T [16][64] bf16 (+pad), 2 buffers
  __shared__ float sWSum[4][16];
  __shared__ float sMaskB[CHUNK];

  const int tid = threadIdx.x;
  const int w   = tid >> 6;      // wave 0..7
  const int l   = tid & 63;
  const int l15 = l & 15;
  const int lhi = l >> 4;        // 0..3
  const int bid = blockIdx.x;
  const int b   = bid >> 4;
  const int chunk0 = (bid & 15) * CHUNK;

  // O^T init (8 real heads only; GEMM2 zero-fills lanes l15>=8)
  for (int idx = tid; idx < 8 * 256; idx += 512){
    int h = idx >> 8, k = idx & 255;
    *(unsigned short*)(sOT + h * 528 + k * 2) = f2bf(ok[k * 8 + h]);
  }
  sMaskB[tid] = mask[(size_t)b * S_LEN + chunk0 + tid] ? 0.0f : 1e12f;

  // persistent K^T fragments built directly from kk (fp32, transposed reads) [R18]
  short8 aF[2][8];
  #pragma unroll
  for (int mi = 0; mi < 2; ++mi){
    int hidA = l15 + ((2*w + mi) << 4);
    #pragma unroll
    for (int k8 = 0; k8 < 8; ++k8){
      int col = (k8 << 5) + (lhi << 3);
      short8 v;
      #pragma unroll
      for (int e = 0; e < 8; ++e)
        v[e] = (short)f2bf(kk[(size_t)(col + e) * 256 + hidA]);
      aF[mi][k8] = v;
    }
  }

  const unsigned char* xb = (const unsigned char*)(x + ((size_t)b * S_LEN + chunk0) * DIM);
  const int dblk = l >> 2;

  // ---- prologue: tile 0 -> regs -> stage sXB + sXT2[0]; then load xr <- tile 1
  f32x4 xr[8];
  #pragma unroll
  for (int q = 0; q < 8; ++q)
    xr[q] = *(const f32x4*)(xb + (((size_t)(8*w + q)) * DIM + 4*l) * 4);

  {
    unsigned vd[8][2];
    #pragma unroll
    for (int q = 0; q < 8; ++q){
      vd[q][0] = pk2bf(xr[q][0], xr[q][1]);
      vd[q][1] = pk2bf(xr[q][2], xr[q][3]);
    }
    #pragma unroll
    for (int q = 0; q < 8; ++q){
      int r = 8*w + q;
      int srow = r ^ (dblk & 3);
      int off = ((l & 3) * 8) ^ (((srow >> 2) & 1) << 4);
      *(uint2*)(sXB + dblk * 2048 + srow * 32 + off) = make_uint2(vd[q][0], vd[q][1]);
    }
    #pragma unroll
    for (int i = 0; i < 4; ++i){
      int hh = i >> 1;
      unsigned dwv[4];
      #pragma unroll
      for (int j = 0; j < 4; ++j){
        unsigned a = vd[2*j][hh], c = vd[2*j+1][hh];
        dwv[j] = (i & 1) ? ((a >> 16) | (c & 0xFFFF0000u)) : ((a & 0xFFFFu) | (c << 16));
      }
      int d = 4*l + i;
      int key = ((d & 3) << 1) ^ ((d >> 2) & 7);
      *(u32x4*)(sXT2 + d * 128 + ((16*w) ^ (key << 4))) = (u32x4){dwv[0],dwv[1],dwv[2],dwv[3]};
    }
  }
  #pragma unroll
  for (int q = 0; q < 8; ++q)
    xr[q] = *(const f32x4*)(xb + (((size_t)(TB + 8*w + q)) * DIM + 4*l) * 4);

  f32x4 acc3[2];
  acc3[0] = (f32x4){0.f,0.f,0.f,0.f};
  acc3[1] = acc3[0];
  float Lrun = 0.0f;    // per-lane partial; shuffle-reduced once in epilogue

  __syncthreads();

  for (int it = 0; it < NIT; ++it){
    // ======== Phase A: GEMM3(it-1) || GEMM1(it) + tanh -> sT2 ========
    if (it > 0){
      const int pb = (it - 1) & 1;
      short8 aP0 = *(const short8*)(sPT + pb * 2304 + l15 * 144 + lhi * 16);       // r 0..31
      short8 aP1 = *(const short8*)(sPT + pb * 2304 + l15 * 144 + 64 + lhi * 16);  // r 32..63
      const unsigned char* srcX = sXT2 + pb * 32768;
      #pragma unroll
      for (int mi = 0; mi < 2; ++mi){
        int d = (2*w + mi) * 16 + l15;
        int key = ((d & 3) << 1) ^ ((d >> 2) & 7);
        const unsigned char* pd = srcX + d * 128;
        short8 b0 = *(const short8*)(pd + (((     lhi * 16)) ^ (key << 4)));
        short8 b1 = *(const short8*)(pd + (((64 + lhi * 16)) ^ (key << 4)));
        acc3[mi] = mfma_bf16(aP0, b0, acc3[mi]);
        acc3[mi] = mfma_bf16(aP1, b1, acc3[mi]);
      }
    }
    #pragma unroll
    for (int nt = 0; nt < 4; ++nt){
      int row = l15 + (nt << 4);
      f32x4 a0 = (f32x4){0.f,0.f,0.f,0.f};
      f32x4 a1 = a0;
      __builtin_amdgcn_s_setprio(1);
      #pragma unroll
      for (int k8 = 0; k8 < 8; ++k8){
        int dblkR = k8 * 2 + (lhi >> 1);
        int srowB = row ^ (dblkR & 3);
        int off = ((lhi & 1) * 16) ^ (((srowB >> 2) & 1) << 4);
        short8 bF = *(const short8*)(sXB + dblkR * 2048 + srowB * 32 + off);
        a0 = mfma_bf16(aF[0][k8], bF, a0);
        a1 = mfma_bf16(aF[1][k8], bF, a1);
      }
      __builtin_amdgcn_s_setprio(0);
      #pragma unroll
      for (int mi = 0; mi < 2; ++mi){
        f32x4 av = mi ? a1 : a0;
        u16x4 tv;
        #pragma unroll
        for (int r = 0; r < 4; ++r) tv[r] = f2bf(fast_tanh(av[r]));
        int hidb2 = ((((2*w + mi) << 4) + (lhi << 2))) * 2;
        *(u16x4*)(sT2 + row * 512 + (hidb2 ^ ((row & 7) << 4))) = tv;
      }
    }
    softbar();

    // ======== Phase B: GEMM2(it)+exp (waves 0-3) || stage tile it+1 || prefetch it+2 ========
    if (it + 1 < NIT){
      unsigned vd[8][2];
      #pragma unroll
      for (int q = 0; q < 8; ++q){
        vd[q][0] = pk2bf(xr[q][0], xr[q][1]);
        vd[q][1] = pk2bf(xr[q][2], xr[q][3]);
      }
      #pragma unroll
      for (int q = 0; q < 8; ++q){
        int r = 8*w + q;
        int srow = r ^ (dblk & 3);
        int off = ((l & 3) * 8) ^ (((srow >> 2) & 1) << 4);
        *(uint2*)(sXB + dblk * 2048 + srow * 32 + off) = make_uint2(vd[q][0], vd[q][1]);
      }
      unsigned char* dst = sXT2 + ((it + 1) & 1) * 32768;
      #pragma unroll
      for (int i = 0; i < 4; ++i){
        int hh = i >> 1;
        unsigned dwv[4];
        #pragma unroll
        for (int j = 0; j < 4; ++j){
          unsigned a = vd[2*j][hh], c = vd[2*j+1][hh];
          dwv[j] = (i & 1) ? ((a >> 16) | (c & 0xFFFF0000u)) : ((a & 0xFFFFu) | (c << 16));
        }
        int d = 4*l + i;
        int key = ((d & 3) << 1) ^ ((d >> 2) & 7);
        *(u32x4*)(dst + d * 128 + ((16*w) ^ (key << 4))) = (u32x4){dwv[0],dwv[1],dwv[2],dwv[3]};
      }
    }
    if (w < 4){
      int row = l15 + (w << 4);
      // dual accumulator: halves the serial MFMA chain (k 0-3 || k 4-7)
      f32x4 a2a = (f32x4){0.f,0.f,0.f,0.f};
      f32x4 a2b = a2a;
      __builtin_amdgcn_s_setprio(1);
      #pragma unroll
      for (int k = 0; k < 4; ++k){
        int col2a = (k << 6) + (lhi << 4);
        int col2b = ((k + 4) << 6) + (lhi << 4);
        short8 aTa = *(const short8*)(sT2 + row * 512 + (col2a ^ ((row & 7) << 4)));
        short8 aTb = *(const short8*)(sT2 + row * 512 + (col2b ^ ((row & 7) << 4)));
        short8 bOa = (l15 < 8) ? *(const short8*)(sOT + l15 * 528 + col2a)
                               : (short8){0,0,0,0,0,0,0,0};
        short8 bOb = (l15 < 8) ? *(const short8*)(sOT + l15 * 528 + col2b)
                               : (short8){0,0,0,0,0,0,0,0};
        a2a = mfma_bf16(aTa, bOa, a2a);
        a2b = mfma_bf16(aTb, bOb, a2b);
      }
      __builtin_amdgcn_s_setprio(0);
      f32x4 a2 = a2a + a2b;
      int rbase = (w << 4) + (lhi << 2);
      #pragma unroll
      for (int r = 0; r < 4; ++r){
        // no-max softmax [R11-verified]: |sc| small; masked rows exp(-1e12)=0
        float p = __expf(a2[r] - sMaskB[it * TB + rbase + r]);
        unsigned short pb2 = f2bf(p);
        Lrun += bf2f(pb2);          // per-lane partial; reduced in epilogue
        *(unsigned short*)(sPT + (it & 1) * 2304 + l15 * 144 + (rbase + r) * 2) = pb2;
      }
    }
    if (it + 2 < NIT){
      #pragma unroll
      for (int q = 0; q < 8; ++q)
        xr[q] = *(const f32x4*)(xb + (((size_t)((it+2)*TB + 8*w + q)) * DIM + 4*l) * 4);
    }
    softbar();
  }

  // ---- epilogue GEMM3 for the last tile ----
  {
    const int pb = (NIT - 1) & 1;
    short8 aP0 = *(const short8*)(sPT + pb * 2304 + l15 * 144 + lhi * 16);
    short8 aP1 = *(const short8*)(sPT + pb * 2304 + l15 * 144 + 64 + lhi * 16);
    const unsigned char* srcX = sXT2 + pb * 32768;
    #pragma unroll
    for (int mi = 0; mi < 2; ++mi){
      int d = (2*w + mi) * 16 + l15;
      int key = ((d & 3) << 1) ^ ((d >> 2) & 7);
      const unsigned char* pd = srcX + d * 128;
      short8 b0 = *(const short8*)(pd + (((     lhi * 16)) ^ (key << 4)));
      short8 b1 = *(const short8*)(pd + (((64 + lhi * 16)) ^ (key << 4)));
      acc3[mi] = mfma_bf16(aP0, b0, acc3[mi]);
      acc3[mi] = mfma_bf16(aP1, b1, acc3[mi]);
    }
  }

  // epilogue: per-chunk partials.  acc3[mi]: head = lhi*4+reg, d = (2w+mi)*16 + l15
  if (lhi < 2){      // only heads 0..7 are real
    #pragma unroll
    for (int mi = 0; mi < 2; ++mi){
      int d = ((2*w + mi) << 4) + l15;
      #pragma unroll
      for (int r = 0; r < 4; ++r){
        int h = (lhi << 2) + r;
        ACC[((size_t)bid * 8 + h) * 256 + d] = acc3[mi][r];
      }
    }
  }
  if (w < 4){
    Lrun += __shfl_xor(Lrun, 16);
    Lrun += __shfl_xor(Lrun, 32);
    if (l < 16) sWSum[w][l] = Lrun;
  }
  __syncthreads();
  if (tid < 8)
    ML[bid * 8 + tid] = sWSum[0][tid] + sWSum[1][tid] + sWSum[2][tid] + sWSum[3][tid];
}

// ---- merge 16 chunk-partials per (batch, head): no max needed (fixed shift = 0)
__global__ void k_merge(const float* __restrict__ ACC, const float* __restrict__ ML,
                        float* __restrict__ out){
  int b = blockIdx.x >> 3;
  int h = blockIdx.x & 7;
  int d = threadIdx.x;                      // 256
  float L = 0.0f, V = 0.0f;
  #pragma unroll 4
  for (int c = 0; c < 16; ++c){
    int blk = b * 16 + c;
    L += ML[blk * 8 + h];
    V += ACC[((size_t)blk * 8 + h) * 256 + d];
  }
  out[(size_t)b * 2048 + h * 256 + d] = V / L;
}

extern "C" void kernel_launch(void* const* d_in, const int* in_sizes, int n_in,
                              void* d_out, int out_size, void* d_ws, size_t ws_size,
                              hipStream_t stream){
  const float* x   = (const float*)d_in[0];
  const int*  mask = (const int*) d_in[1];
  const float* kk  = (const float*)d_in[2];
  const float* ok  = (const float*)d_in[3];
  float* out = (float*)d_out;

  // ws layout: ACC f32 256*8*256 (2 MiB) | ML f32 256*8 (8 KiB)
  float* ACC = (float*)d_ws;
  float* ML  = (float*)((char*)d_ws + 2097152);

  k_main <<<NBLK, 512, 0, stream>>>(x, mask, ok, kk, ACC, ML);
  k_merge<<<128, 256, 0, stream>>>(ACC, ML, out);
}